// Round 1
// baseline (506.950 us; speedup 1.0000x reference)
//
#include <hip/hip_runtime.h>

// PowerSpectrum: out[s,n, l*f^2 + i*f + j] = (2l+1)^{-1/2} * sum_m c_l[s,n,m,i]*c_l[s,n,m,j]
// f = 128, m-count = 2l+1 (1,3,5,7), S*N = 2000.
// Write-bound: 524 MB output vs 16 MB input. Target: coalesced float4 stores at HBM ceiling.

#define NFEAT 128

__device__ __constant__ float kCg[4] = {
    1.0f,
    0.57735026918962576451f,   // 1/sqrt(3)
    0.44721359549995793928f,   // 1/sqrt(5)
    0.37796447300922722721f};  // 1/sqrt(7)

template <int L>
__global__ __launch_bounds__(256) void ps_kernel(const float* __restrict__ c,
                                                 float* __restrict__ out) {
  constexpr int NM = 2 * L + 1;
  __shared__ float sc[NM * NFEAT];

  const int sn  = blockIdx.x;
  const int tid = threadIdx.x;

  // Stage this block's c-tile: NM*128 floats = NM*32 float4 (<= 224 <= 256 threads)
  const float* src = c + (size_t)sn * (NM * NFEAT);
  if (tid < NM * 32) {
    ((float4*)sc)[tid] = ((const float4*)src)[tid];
  }
  __syncthreads();

  const int j4 = tid & 31;   // float4 column 0..31  (j = 4*j4 .. 4*j4+3)
  const int i0 = tid >> 5;   // row phase 0..7

  // B fragment: c[m][4*j4 .. 4*j4+3] — registers, compile-time NM
  float4 b[NM];
#pragma unroll
  for (int m = 0; m < NM; ++m) b[m] = ((const float4*)sc)[m * 32 + j4];

  const float cg = kCg[L];
  float* obase = out + (size_t)sn * (4 * NFEAT * NFEAT) + (size_t)L * (NFEAT * NFEAT);

#pragma unroll
  for (int k = 0; k < 16; ++k) {
    const int i = i0 + 8 * k;  // 4 waves cover 8 contiguous rows per pass
    float4 acc = {0.f, 0.f, 0.f, 0.f};
#pragma unroll
    for (int m = 0; m < NM; ++m) {
      const float a = sc[m * NFEAT + i];  // wave-broadcast LDS read
      acc.x += a * b[m].x;
      acc.y += a * b[m].y;
      acc.z += a * b[m].z;
      acc.w += a * b[m].w;
    }
    acc.x *= cg; acc.y *= cg; acc.z *= cg; acc.w *= cg;
    ((float4*)(obase + i * NFEAT))[j4] = acc;
  }
}

extern "C" void kernel_launch(void* const* d_in, const int* in_sizes, int n_in,
                              void* d_out, int out_size, void* d_ws, size_t ws_size,
                              hipStream_t stream) {
  const float* c0 = (const float*)d_in[0];
  const float* c1 = (const float*)d_in[1];
  const float* c2 = (const float*)d_in[2];
  const float* c3 = (const float*)d_in[3];
  float* out = (float*)d_out;

  // S*N from l=0 input: (S, N, 1, 128) -> S*N = size/128
  const int nsn = in_sizes[0] / NFEAT;

  dim3 block(256);
  dim3 grid(nsn);
  ps_kernel<0><<<grid, block, 0, stream>>>(c0, out);
  ps_kernel<1><<<grid, block, 0, stream>>>(c1, out);
  ps_kernel<2><<<grid, block, 0, stream>>>(c2, out);
  ps_kernel<3><<<grid, block, 0, stream>>>(c3, out);
}